// Round 11
// baseline (146.359 us; speedup 1.0000x reference)
//
#include <hip/hip_runtime.h>
#include <hip/hip_bf16.h>

#define DI __device__ __forceinline__
#define MFMA __builtin_amdgcn_mfma_f32_16x16x32_bf16

typedef __attribute__((ext_vector_type(8))) short bf16x8;   // 8 bf16 = 4 VGPRs (MFMA A/B frag)
typedef __attribute__((ext_vector_type(4))) short s16x4;    // 4 bf16 = 8 B (ds_write_b64)
typedef __attribute__((ext_vector_type(4))) float f32x4;    // MFMA C/D frag

constexpr int HW = 4096;
constexpr int SAS = 72;            // ic-stride in shorts (36 dwords -> 2-way banks, free)
constexpr int FR  = 66 * SAS;      // 4752 shorts per frame (66 cols x 72)

// ---- workspace layout (bytes): weights only (~240 KB) ----
constexpr size_t OFF_WB3  = 0;                       // bf16 [3][9][64oc][64ic]
constexpr size_t OFF_WB1  = OFF_WB3 + 221184;        // bf16 [2][64oc][64ic]
constexpr size_t OFF_BIAS = OFF_WB1 + 16384;         // f32 [5][64]
constexpr size_t OFF_CC   = OFF_BIAS + 1280;         // int[2]

DI int argmax8(const float* __restrict__ a) {
    int best = 0; float bv = a[0];
#pragma unroll
    for (int i = 1; i < 8; ++i) { float v = a[i]; if (v > bv) { bv = v; best = i; } }
    return best;
}

DI short f2bf(float v) {
    __hip_bfloat16 h = __float2bfloat16(v);
    return __builtin_bit_cast(short, h);
}

DI float bf2f(short s) {
    return __bfloat162float(__builtin_bit_cast(__hip_bfloat16, s));
}

// ---------------------------------------------------------------------------
// prep: c1,c2; weights -> bf16 frag order with BN scale + channel masks
// folded; per-edge bias (out-masked). Tiny kernel (~3 us).
// ---------------------------------------------------------------------------
__global__ __launch_bounds__(256) void prep_kernel(
    const float* __restrict__ w3, const float* __restrict__ w1,
    const float* __restrict__ bn, const float* __restrict__ a1,
    const float* __restrict__ a2, char* __restrict__ ws) {
    short* __restrict__ wb3  = (short*)(ws + OFF_WB3);
    short* __restrict__ wb1  = (short*)(ws + OFF_WB1);
    float* __restrict__ bias = (float*)(ws + OFF_BIAS);
    int*   __restrict__ cc   = (int*)(ws + OFF_CC);
    const int c1 = 8 * (argmax8(a1) + 1);
    const int c2 = 8 * (argmax8(a2) + 1);

    const int idx = blockIdx.x * 256 + threadIdx.x;
    if (idx < 110592) {                       // wb3 flat = ((e*9+kp)*64+oc)*64+ic
        const int e = idx / 36864, rem = idx % 36864;
        const int kp = rem >> 12, oc = (rem >> 6) & 63, ic = rem & 63;
        const int bnrow = (e == 0) ? 0 : (e == 1) ? 1 : 3;
        const float g = bn[(bnrow * 4 + 0) * 64 + oc];
        const float v = bn[(bnrow * 4 + 3) * 64 + oc];
        const float s = g * rsqrtf(v + 1e-5f);
        const float wv = w3[((e * 64 + oc) * 64 + ic) * 9 + kp];
        wb3[idx] = (oc < c2 && ic < c1) ? f2bf(wv * s) : (short)0;
    } else if (idx < 118784) {                // wb1 flat = (e*64+oc)*64+ic
        const int j = idx - 110592;
        const int e = j >> 12, oc = (j >> 6) & 63, ic = j & 63;
        const int bnrow = (e == 0) ? 2 : 4;
        const float g = bn[(bnrow * 4 + 0) * 64 + oc];
        const float v = bn[(bnrow * 4 + 3) * 64 + oc];
        const float s = g * rsqrtf(v + 1e-5f);
        wb1[j] = (oc < c2 && ic < c1) ? f2bf(w1[(e * 64 + oc) * 64 + ic] * s) : (short)0;
    } else if (idx < 119104) {                // bias
        const int j = idx - 118784;
        const int e = j >> 6, oc = j & 63;
        const float g = bn[(e * 4 + 0) * 64 + oc];
        const float b = bn[(e * 4 + 1) * 64 + oc];
        const float m = bn[(e * 4 + 2) * 64 + oc];
        const float v = bn[(e * 4 + 3) * 64 + oc];
        bias[j] = (oc < c2) ? (b - m * g * rsqrtf(v + 1e-5f)) : 0.f;
    } else if (idx == 119104) {
        cc[0] = c1; cc[1] = c2;
    }
}

// ---------------------------------------------------------------------------
// conv helpers: conv3_sw1 / conv3_nm1 are the R4-verified FULLY UNROLLED
// versions (scheduler pipelines weight loads + ds_reads across the 9
// straight-line steps). conv1/epi helpers identical in R3 and R4.
// No setprio (R7 lesson). All register indices compile-time.
// ---------------------------------------------------------------------------
// 3x3 conv, one full row, SWAPPED operands (lane: px=mt*16+lm, oc=nt*16+q*4+r)
DI void conv3_sw1(const short* __restrict__ sA, int f0,
                  const short* __restrict__ WB, int c1, int c2,
                  int lm, int q, f32x4 (&acc)[4][4]) {
#pragma unroll
    for (int ky = 0; ky < 3; ++ky)
#pragma unroll
        for (int kx = 0; kx < 3; ++kx) {
            const short* __restrict__ W = WB + (ky * 3 + kx) * 4096;
#pragma unroll
            for (int kc = 0; kc < 2; ++kc)
                if (kc == 0 || c1 > 32) {
                    bf16x8 af[4], bfr[4];
#pragma unroll
                    for (int nt = 0; nt < 4; ++nt)
                        if (nt * 16 < c2)
                            bfr[nt] = *(const bf16x8*)(W + (nt * 16 + lm) * 64 + kc * 32 + q * 8);
#pragma unroll
                    for (int mt = 0; mt < 4; ++mt)
                        af[mt] = *(const bf16x8*)(&sA[((f0 + ky) * 66 + mt * 16 + lm + kx) * SAS + kc * 32 + q * 8]);
#pragma unroll
                    for (int nt = 0; nt < 4; ++nt)
                        if (nt * 16 < c2)
#pragma unroll
                            for (int mt = 0; mt < 4; ++mt)
                                acc[mt][nt] = MFMA(bfr[nt], af[mt], acc[mt][nt], 0, 0, 0);
                }
        }
}

// 3x3 conv, one full row, NORMAL operands (lane: oc=nt*16+lm, px=mt*16+q*4+r)
DI void conv3_nm1(const short* __restrict__ sA, int f0,
                  const short* __restrict__ WB, int c1, int c2,
                  int lm, int q, f32x4 (&acc)[4][4]) {
#pragma unroll
    for (int ky = 0; ky < 3; ++ky)
#pragma unroll
        for (int kx = 0; kx < 3; ++kx) {
            const short* __restrict__ W = WB + (ky * 3 + kx) * 4096;
#pragma unroll
            for (int kc = 0; kc < 2; ++kc)
                if (kc == 0 || c1 > 32) {
                    bf16x8 af[4], bfr[4];
#pragma unroll
                    for (int nt = 0; nt < 4; ++nt)
                        if (nt * 16 < c2)
                            bfr[nt] = *(const bf16x8*)(W + (nt * 16 + lm) * 64 + kc * 32 + q * 8);
#pragma unroll
                    for (int mt = 0; mt < 4; ++mt)
                        af[mt] = *(const bf16x8*)(&sA[((f0 + ky) * 66 + mt * 16 + lm + kx) * SAS + kc * 32 + q * 8]);
#pragma unroll
                    for (int nt = 0; nt < 4; ++nt)
                        if (nt * 16 < c2)
#pragma unroll
                            for (int mt = 0; mt < 4; ++mt)
                                acc[mt][nt] = MFMA(af[mt], bfr[nt], acc[mt][nt], 0, 0, 0);
                }
        }
}

// 1x1 conv, swapped, accumulate (input = n1 slot row, col = px+1)
DI void conv1_sw(const short* __restrict__ sRow, const short* __restrict__ W1,
                 int c1, int c2, int lm, int q, f32x4 (&acc)[4][4]) {
#pragma unroll
    for (int kc = 0; kc < 2; ++kc)
        if (kc == 0 || c1 > 32) {
            bf16x8 af[4], bfr[4];
#pragma unroll
            for (int mt = 0; mt < 4; ++mt)
                af[mt] = *(const bf16x8*)(&sRow[(mt * 16 + lm + 1) * SAS + kc * 32 + q * 8]);
#pragma unroll
            for (int nt = 0; nt < 4; ++nt)
                if (nt * 16 < c2)
                    bfr[nt] = *(const bf16x8*)(W1 + (nt * 16 + lm) * 64 + kc * 32 + q * 8);
#pragma unroll
            for (int nt = 0; nt < 4; ++nt)
                if (nt * 16 < c2)
#pragma unroll
                    for (int mt = 0; mt < 4; ++mt)
                        acc[mt][nt] = MFMA(bfr[nt], af[mt], acc[mt][nt], 0, 0, 0);
        }
}

// 1x1 conv, normal, accumulate (input = [px][ic] row, no col halo)
DI void conv1_nm(const short* __restrict__ sRow, const short* __restrict__ W1,
                 int c1, int c2, int lm, int q, f32x4 (&acc)[4][4]) {
#pragma unroll
    for (int kc = 0; kc < 2; ++kc)
        if (kc == 0 || c1 > 32) {
            bf16x8 af[4], bfr[4];
#pragma unroll
            for (int mt = 0; mt < 4; ++mt)
                af[mt] = *(const bf16x8*)(&sRow[(mt * 16 + lm) * SAS + kc * 32 + q * 8]);
#pragma unroll
            for (int nt = 0; nt < 4; ++nt)
                if (nt * 16 < c2)
                    bfr[nt] = *(const bf16x8*)(W1 + (nt * 16 + lm) * 64 + kc * 32 + q * 8);
#pragma unroll
            for (int nt = 0; nt < 4; ++nt)
                if (nt * 16 < c2)
#pragma unroll
                    for (int mt = 0; mt < 4; ++mt)
                        acc[mt][nt] = MFMA(af[mt], bfr[nt], acc[mt][nt], 0, 0, 0);
        }
}

// relu+bias epi from a SWAPPED acc into a [px][stride SAS] row.
DI void epi_sw(short* __restrict__ dst, int colOff, const float* __restrict__ b0,
               const float* __restrict__ b1, bool live, int lm, int q,
               const f32x4 (&acc)[4][4]) {
#pragma unroll
    for (int nt = 0; nt < 4; ++nt) {
        f32x4 bv = *(const f32x4*)(b0 + nt * 16 + q * 4);
        if (b1) {
            const f32x4 bvb = *(const f32x4*)(b1 + nt * 16 + q * 4);
#pragma unroll
            for (int r = 0; r < 4; ++r) bv[r] += bvb[r];
        }
#pragma unroll
        for (int mt = 0; mt < 4; ++mt) {
            s16x4 pk = (s16x4)0;
            if (live) {
#pragma unroll
                for (int r = 0; r < 4; ++r)
                    pk[r] = f2bf(fmaxf(acc[mt][nt][r] + bv[r], 0.f));
            }
            *(s16x4*)(&dst[(mt * 16 + lm + colOff) * SAS + nt * 16 + q * 4]) = pk;
        }
    }
}

// ---------------------------------------------------------------------------
// Fused cell kernel: ROUND-3 VERIFIED dataflow (2 out rows, 6 waves, 57 KB
// static LDS -> 2 blocks/CU co-resident), with the only change being the
// R4-verified UNROLLED conv3 helpers. Frames 0-5 = x rows y0-2..y0+3;
// after B2 frames 0-3 = n1 rows y0-1..y0+2; frames 4,5 = n2 then p3
// (in-place, same-wave, verified in R3).
// P1: w0-3 e0 rows y0-1..y0+2 | w4,w5 e1 rows y0,y0+1  (one acc each).
// P2: w0,w1 e2 rows | w4,w5 conv1_e0 -> n2 -> conv1_e1 -> p3.
// P3: w0,w1 combine + coalesced f32x4 store.
// ---------------------------------------------------------------------------
__global__ __launch_bounds__(384, 3) void fused_cell_kernel(
    const float* __restrict__ x, const char* __restrict__ ws,
    float* __restrict__ outp) {
    __shared__ __align__(16) short sA[6 * FR];   // 57,024 B
    const int t = threadIdx.x, w = t >> 6, l = t & 63, lm = l & 15, q = l >> 4;
    const int y0 = blockIdx.x * 2, n = blockIdx.y;
    const int* cc = (const int*)(ws + OFF_CC);
    const int c1 = __builtin_amdgcn_readfirstlane(cc[0]);
    const int c2 = __builtin_amdgcn_readfirstlane(cc[1]);
    const int SGm = (c1 > 32) ? 8 : 4;
    const float* __restrict__ bias = (const float*)(ws + OFF_BIAS);
    const short* __restrict__ WBe0 = (const short*)(ws + OFF_WB3);
    const short* __restrict__ WBe1 = WBe0 + 36864;
    const short* __restrict__ WBe2 = WBe0 + 2 * 36864;
    const short* __restrict__ W1e0 = (const short*)(ws + OFF_WB1);
    const short* __restrict__ W1e1 = W1e0 + 4096;

    // ---- P0: stage 6 x frames (fused relu + bf16 + transpose) ----
    if (t < 96) {    // zero halo cols 0,65 of all 6 frames
        const int r = t >> 4, chp = (t >> 3) & 1, sg = t & 7;
        *(bf16x8*)(&sA[(r * 66 + chp * 65) * SAS + sg * 8]) = (bf16x8)0;
    }
    {   // wave w stages frame w (x row y0-2+w), live ic-groups only
        const int gy = y0 - 2 + w;
#pragma unroll 1
        for (int icg = 0; icg < 8; ++icg) {
            if (icg < SGm) {                  // wave-uniform ic cull
                const float* __restrict__ src = x + (((size_t)n * 64 + icg * 8) * 64 + gy) * 64 + l;
                bf16x8 pk = (bf16x8)0;
                if ((unsigned)gy < 64u) {     // wave-uniform y-halo check
#pragma unroll
                    for (int j = 0; j < 8; ++j)
                        pk[j] = f2bf(fmaxf(src[j * HW], 0.f));
                }
                *(bf16x8*)(&sA[(w * 66 + l + 1) * SAS + icg * 8]) = pk;
            }
        }
    }
    __syncthreads();   // B1: frames ready

    // ---- P1: one conv3 per wave (unrolled, single acc) ----
    f32x4 acc[4][4];
#pragma unroll
    for (int i = 0; i < 4; ++i)
#pragma unroll
        for (int j = 0; j < 4; ++j) acc[i][j] = 0.f;

    if (w < 4) {
        conv3_sw1(sA, w, WBe0, c1, c2, lm, q, acc);            // e0 -> n1 row y0-1+w
    } else {
        conv3_sw1(sA, (w - 4) + 1, WBe1, c1, c2, lm, q, acc);  // e1 -> out row y0+(w-4)
    }
    __syncthreads();   // B2: all x reads done -> frames may be overwritten

    // ---- n1 epi: w0-3 -> frames 0-3 (zeros for OOB rows) ----
    if (w < 4) {
        const int gy = y0 - 1 + w;
        epi_sw(&sA[w * FR], 1, bias, nullptr, (unsigned)gy < 64u, lm, q, acc);
    }
    __syncthreads();   // B3: n1 ready

    // ---- P2 ----
    if (w < 2) {
        // e2 out row y0+w <- n1 slots w..w+2 (normal layout)
#pragma unroll
        for (int i = 0; i < 4; ++i)
#pragma unroll
            for (int j = 0; j < 4; ++j) acc[i][j] = 0.f;
        conv3_nm1(sA, w, WBe2, c1, c2, lm, q, acc);
    } else if (w >= 4) {
        const int j = w - 4;
        short* __restrict__ scr = &sA[(4 + j) * FR];           // frames 4,5: dead x
        // conv1_e0(n1 row y0+j = frame j+1) accumulates into the e1 acc
        conv1_sw(&sA[(j + 1) * FR], W1e0, c1, c2, lm, q, acc);
        // n2 = relu(acc + b1 + b2) -> scr as [px][ic] (b64 writes)
        epi_sw(scr, 0, bias + 64, bias + 128, true, lm, q, acc);
        // conv1_e1 (normal order) from scr
#pragma unroll
        for (int i = 0; i < 4; ++i)
#pragma unroll
            for (int j2 = 0; j2 < 4; ++j2) acc[i][j2] = 0.f;
        conv1_nm(scr, W1e1, c1, c2, lm, q, acc);
        // p3 epi -> same frame, [oc][px] layout (same-wave WAR via lgkmcnt)
#pragma unroll
        for (int nt = 0; nt < 4; ++nt) {
            const float bva = bias[256 + nt * 16 + lm];
#pragma unroll
            for (int mt = 0; mt < 4; ++mt) {
                s16x4 pk;
#pragma unroll
                for (int r = 0; r < 4; ++r)
                    pk[r] = f2bf(acc[mt][nt][r] + bva);
                *(s16x4*)(&scr[(nt * 16 + lm) * SAS + mt * 16 + q * 4]) = pk;
            }
        }
    }
    __syncthreads();   // B4: e2 + p3 ready

    // ---- P3: combine + coalesced f32x4 store (w0,w1 own out rows 0,1) ----
    if (w < 2) {
        const int y = y0 + w;
        const short* __restrict__ p3r = &sA[(4 + w) * FR];
        const float* __restrict__ bias3 = bias + 192;
#pragma unroll
        for (int nt = 0; nt < 4; ++nt) {
            const int oc = nt * 16 + lm;
            const float bvs = bias3[oc];
#pragma unroll
            for (int mt = 0; mt < 4; ++mt) {
                const s16x4 p = *(const s16x4*)(&p3r[oc * SAS + mt * 16 + q * 4]);
                const size_t ob = (((size_t)n * 64 + oc) * 64 + y) * 64 + mt * 16 + q * 4;
                const f32x4 s = *(const f32x4*)(x + ob);   // skip = raw x
                f32x4 v;
#pragma unroll
                for (int r = 0; r < 4; ++r)
                    v[r] = acc[mt][nt][r] + bvs + bf2f(p[r]) + s[r];
                *(f32x4*)(outp + ob) = v;   // oc>=c2: acc=bias=p3=0 -> skip only
            }
        }
    }
}

// ---------------------------------------------------------------------------
extern "C" void kernel_launch(void* const* d_in, const int* in_sizes, int n_in,
                              void* d_out, int out_size, void* d_ws, size_t ws_size,
                              hipStream_t stream) {
    (void)in_sizes; (void)n_in; (void)out_size; (void)ws_size;
    const float* x  = (const float*)d_in[0];
    const float* a1 = (const float*)d_in[1];
    const float* a2 = (const float*)d_in[2];
    const float* w3 = (const float*)d_in[3];
    const float* w1 = (const float*)d_in[4];
    const float* bn = (const float*)d_in[5];
    char* ws = (char*)d_ws;

    prep_kernel<<<466, 256, 0, stream>>>(w3, w1, bn, a1, a2, ws);
    const dim3 gc(32, 32);   // y-tiles of 2 rows, n
    fused_cell_kernel<<<gc, 384, 0, stream>>>(x, ws, (float*)d_out);
}